// Round 14
// baseline (156.284 us; speedup 1.0000x reference)
//
#include <hip/hip_runtime.h>
#include <hip/hip_bf16.h>
#include <cstdint>
#include <cstddef>

#define NV    8192   // nodes
#define KIN   512    // in features
#define MOUT  128    // out features
#define LOG2E 1.4426950408889634f

typedef __attribute__((ext_vector_type(4))) float f32x4;
typedef __attribute__((ext_vector_type(8))) short short8;

__device__ __forceinline__ float elu1(float x) { return x > 0.f ? x : expm1f(x); }

__device__ __forceinline__ unsigned int pkbf2(float a, float b) {
  union { __hip_bfloat162 h2; unsigned int u; } r;
  r.h2 = __float22bfloat162_rn(make_float2(a, b));
  return r.u;
}

// ---------------- kernel 1: wh1/wh2 (log2-scaled) + fragB (bf16, MFMA-fragment order) ----------------
// fragB[jt][cg][ks][lane][e] = bf16(wh[jt*64+ks*32+(lane>>4)*8+e][cg*16+(lane&15)])
__global__ __launch_bounds__(256) void k_wh(const float* __restrict__ h,
                                            const float* __restrict__ w,
                                            const float* __restrict__ a1,
                                            const float* __restrict__ a2,
                                            unsigned short* __restrict__ fragB,
                                            float* __restrict__ wh1,
                                            float* __restrict__ wh2) {
  __shared__ __align__(16) float hT[64][36];
  __shared__ __align__(16) float wT[64][128];
  const int t = threadIdx.x;
  const int row0 = blockIdx.x * 32;
  const int hr = t >> 3, hu = t & 7;
  const int wc = t >> 1, whalf = t & 1;
  const int cg = t & 31, rg = t >> 5;
  const int c0 = cg * 4, r0 = rg * 4;
  float acc[4][4] = {};

  for (int kt = 0; kt < 8; ++kt) {
    const int k0 = kt * 64;
    __syncthreads();
#pragma unroll
    for (int v = 0; v < 8; ++v)
      hT[hu + 8 * v][hr] = h[(size_t)(row0 + hr) * KIN + k0 + hu + 8 * v];
#pragma unroll
    for (int mv = 0; mv < 8; ++mv) {
      const float4 wv4 = *(const float4*)&w[(size_t)wc * KIN + k0 + whalf * 32 + mv * 4];
      wT[whalf * 32 + mv * 4 + 0][wc] = wv4.x;
      wT[whalf * 32 + mv * 4 + 1][wc] = wv4.y;
      wT[whalf * 32 + mv * 4 + 2][wc] = wv4.z;
      wT[whalf * 32 + mv * 4 + 3][wc] = wv4.w;
    }
    __syncthreads();
#pragma unroll 8
    for (int kk = 0; kk < 64; ++kk) {
      const float4 hv = *(const float4*)&hT[kk][r0];
      const float4 wv4 = *(const float4*)&wT[kk][c0];
      const float hvv[4] = {hv.x, hv.y, hv.z, hv.w};
      const float wvv[4] = {wv4.x, wv4.y, wv4.z, wv4.w};
#pragma unroll
      for (int i = 0; i < 4; ++i)
#pragma unroll
        for (int j = 0; j < 4; ++j)
          acc[i][j] = fmaf(hvv[i], wvv[j], acc[i][j]);
    }
  }

  // fragB store straight from accumulators
  {
    const size_t jt = (size_t)(row0 >> 6);
    const int ks = (row0 >> 5) & 1;
    const int lg = rg >> 1, ebase = (rg & 1) * 4;
    const int cgf = cg >> 2;
    const size_t fbase = (((jt * 8 + cgf) * 2 + ks) * 64 + lg * 16) * 8 + ebase;
#pragma unroll
    for (int j = 0; j < 4; ++j) {
      const int l15 = (cg & 3) * 4 + j;
      uint2 o;
      o.x = pkbf2(acc[0][j], acc[1][j]);
      o.y = pkbf2(acc[2][j], acc[3][j]);
      *(uint2*)&fragB[fbase + (size_t)l15 * 8] = o;
    }
  }

  const float4 a1v = *(const float4*)&a1[c0];
  const float4 a2v = *(const float4*)&a2[c0];
#pragma unroll
  for (int i = 0; i < 4; ++i) {
    float s1 = acc[i][0] * a1v.x + acc[i][1] * a1v.y + acc[i][2] * a1v.z + acc[i][3] * a1v.w;
    float s2 = acc[i][0] * a2v.x + acc[i][1] * a2v.y + acc[i][2] * a2v.z + acc[i][3] * a2v.w;
#pragma unroll
    for (int off = 16; off > 0; off >>= 1) {
      s1 += __shfl_down(s1, off, 32);
      s2 += __shfl_down(s2, off, 32);
    }
    if (cg == 0) {
      wh1[row0 + r0 + i] = s1 * LOG2E;
      wh2[row0 + r0 + i] = s2 * LOG2E;
    }
  }
}

// ---------------- kernel 2: wave-specialized producer/consumer attention ----------------
// grid 512 x 512 thr (8 waves, 2 blocks/CU). Block owns 16 rows x full j-range.
// Waves 6,7: producers — stream the block's 16x8192 adj slice (4 KB bursts, 8 chunks of
// 16 tiles) into an LDS bitmask, bumping ready[c] per chunk. Waves 0-5: consumers — own
// tiles T = wv mod 6, run the exp/MFMA loop continuously (zero exp redundancy: A-frag
// rows are l15). Epilogue: LDS atomic reduction of 6 partial accs + ones-MFMA denoms ->
// normalize + ELU -> final out. No out_p, no combine kernel, adj stream fully overlapped.
__global__ __launch_bounds__(512, 4) void k_attn(const unsigned short* __restrict__ fragB,
                                                 const int* __restrict__ adj,
                                                 const float* __restrict__ wh1l,
                                                 const float* __restrict__ wh2l,
                                                 float* __restrict__ out) {
  __shared__ char smask[16 * 1032];      // [row][tile] uint2; stride 258 dwords (%32=2, conflict-free)
  __shared__ float ored[16][132];        // reduction area (132: pad, %4==0 for float4)
  __shared__ float odenom[16];
  __shared__ int ready[8];
  const int t = threadIdx.x;
  const int i0 = blockIdx.x * 16;
  const int lane = t & 63, wv = t >> 6;
  const int l15 = lane & 15, lg = lane >> 4;

  // zero flags + reduction area
  {
    float* of = &ored[0][0];
    for (int k = t; k < 16 * 132; k += 512) of[k] = 0.f;
    if (t < 16) odenom[t] = 0.f;
    if (t < 8) ready[t] = 0;
  }
  __syncthreads();

  if (wv >= 6) {
    // ---- producers: 2 waves x 8 rows; chunk c = 16 tiles = 4 KB per row ----
    const int pw = wv - 6;
    for (int c = 0; c < 8; ++c) {
#pragma unroll 2
      for (int r8 = 0; r8 < 8; ++r8) {
        const int row = pw * 8 + r8;
        const int* p = adj + (size_t)(i0 + row) * NV + c * 1024 + lane * 16;
        const int4 v0 = *(const int4*)(p);
        const int4 v1 = *(const int4*)(p + 4);
        const int4 v2 = *(const int4*)(p + 8);
        const int4 v3 = *(const int4*)(p + 12);
        const unsigned int m =
            (unsigned)(v0.x & 1)        | ((unsigned)(v0.y & 1) << 1)  |
            ((unsigned)(v0.z & 1) << 2) | ((unsigned)(v0.w & 1) << 3)  |
            ((unsigned)(v1.x & 1) << 4) | ((unsigned)(v1.y & 1) << 5)  |
            ((unsigned)(v1.z & 1) << 6) | ((unsigned)(v1.w & 1) << 7)  |
            ((unsigned)(v2.x & 1) << 8) | ((unsigned)(v2.y & 1) << 9)  |
            ((unsigned)(v2.z & 1) << 10)| ((unsigned)(v2.w & 1) << 11) |
            ((unsigned)(v3.x & 1) << 12)| ((unsigned)(v3.y & 1) << 13) |
            ((unsigned)(v3.z & 1) << 14)| ((unsigned)(v3.w & 1) << 15);
        *(unsigned short*)&smask[row * 1032 + (c * 16 + (lane >> 2)) * 8 + (lane & 3) * 2] =
            (unsigned short)m;
      }
      __threadfence_block();
      if (lane == 0) atomicAdd(&ready[c], 1);
    }
  } else {
    // ---- consumers: 6 waves; wave owns tiles T = wv, wv+6, ... (16 rows x 128 cols) ----
    const float wh1r = wh1l[i0 + l15];           // A-frag row = l15
    const char* mrow = smask + l15 * 1032;
    const unsigned short* bb = fragB + lane * 8;
    f32x4 acc[8] = {};
    f32x4 accs = {};
    short8 onesf;
#pragma unroll
    for (int e = 0; e < 8; ++e) onesf[e] = (short)0x3F80;  // bf16 1.0

    int nextc = 0;
    for (int T = wv; T < 128; T += 6) {
      const int c = T >> 4;
      while (nextc <= c) {
        while (atomicAdd(&ready[nextc], 0) < 2) __builtin_amdgcn_s_sleep(8);
        ++nextc;
      }
      const uint2 m2 = *(const uint2*)&mrow[T * 8];
      const float* w2p = wh2l + T * 64 + lg * 8;
      const float4 wq0 = *(const float4*)(w2p);
      const float4 wq1 = *(const float4*)(w2p + 4);
      const float4 wq2 = *(const float4*)(w2p + 32);
      const float4 wq3 = *(const float4*)(w2p + 36);
      const unsigned short* bp = bb + (size_t)T * 8192;
#pragma unroll
      for (int ks = 0; ks < 2; ++ks) {
        const float4 wa = ks ? wq2 : wq0;
        const float4 wb = ks ? wq3 : wq1;
        const float w2v[8] = {wa.x, wa.y, wa.z, wa.w, wb.x, wb.y, wb.z, wb.w};
        const unsigned int m8 = ((ks ? m2.y : m2.x) >> (8 * lg)) & 0xFFu;
        union { short8 s8; unsigned int u[4]; } pk;
#pragma unroll
        for (int e = 0; e < 4; ++e) {
          float x0 = wh1r + w2v[2 * e];
          float x1 = wh1r + w2v[2 * e + 1];
          x0 = fmaxf(x0, 0.01f * x0);
          x1 = fmaxf(x1, 0.01f * x1);
          float p0 = __builtin_amdgcn_exp2f(x0);
          float p1 = __builtin_amdgcn_exp2f(x1);
          p0 = ((m8 >> (2 * e)) & 1u) ? p0 : 0.f;
          p1 = ((m8 >> (2 * e + 1)) & 1u) ? p1 : 0.f;
          pk.u[e] = pkbf2(p0, p1);
        }
        const short8 af = pk.s8;
        const unsigned short* bks = bp + ks * 512;
#pragma unroll
        for (int cg = 0; cg < 8; ++cg) {
          const short8 bf = *(const short8*)(bks + cg * 1024);
          acc[cg] = __builtin_amdgcn_mfma_f32_16x16x32_bf16(af, bf, acc[cg], 0, 0, 0);
        }
        accs = __builtin_amdgcn_mfma_f32_16x16x32_bf16(af, onesf, accs, 0, 0, 0);
      }
    }
    // reduce partials into LDS (C/D: lane(l15,lg) reg r -> D[row=lg*4+r][col=cg*16+l15])
#pragma unroll
    for (int cg = 0; cg < 8; ++cg)
#pragma unroll
      for (int r = 0; r < 4; ++r)
        atomicAdd(&ored[lg * 4 + r][cg * 16 + l15], acc[cg][r]);
    if (l15 == 0) {
#pragma unroll
      for (int r = 0; r < 4; ++r)
        atomicAdd(&odenom[lg * 4 + r], accs[r]);
    }
  }
  __syncthreads();

  // ---- finalize: normalize + ELU + store (512 thr x 4 floats = 16x128 tile) ----
  {
    const int row = t >> 5, c4 = (t & 31) * 4;
    const float inv = 1.f / odenom[row];
    const float4 v = *(const float4*)&ored[row][c4];
    float4 o;
    o.x = elu1(v.x * inv);
    o.y = elu1(v.y * inv);
    o.z = elu1(v.z * inv);
    o.w = elu1(v.w * inv);
    *(float4*)&out[(size_t)(i0 + row) * MOUT + c4] = o;
  }
}

extern "C" void kernel_launch(void* const* d_in, const int* in_sizes, int n_in,
                              void* d_out, int out_size, void* d_ws, size_t ws_size,
                              hipStream_t stream) {
  const float* h  = (const float*)d_in[0];
  const int* adj  = (const int*)d_in[1];
  const float* w  = (const float*)d_in[2];
  const float* a1 = (const float*)d_in[3];
  const float* a2 = (const float*)d_in[4];
  float* out = (float*)d_out;

  char* ws = (char*)d_ws;
  // layout: [fragB 2MB][wh1 32KB][wh2 32KB]
  unsigned short* fragB = (unsigned short*)ws;
  size_t off = (size_t)MOUT * NV * 2;
  float* wh1 = (float*)(ws + off); off += (size_t)NV * 4;
  float* wh2 = (float*)(ws + off);

  k_wh<<<NV / 32, 256, 0, stream>>>(h, w, a1, a2, fragB, wh1, wh2);
  k_attn<<<NV / 16, 512, 0, stream>>>(fragB, adj, wh1, wh2, out);
}